// Round 1
// baseline (235.537 us; speedup 1.0000x reference)
//
#include <hip/hip_runtime.h>
#include <math.h>
#include <type_traits>

// SoftMSM loss on MI355X — round 16.
// R14/R15 DP code verbatim; execution config change only:
//   512-thread blocks (8 waves) x 16 blocks, 4 batches per block.
//   Wave w -> chain (batch = blockIdx*4 + (w>>1), dir = w&1).
//   HW round-robins the 8 waves across 4 SIMDs -> 2 independent DP chains
//   per SIMD, so one wave issues while the other sits in its serial
//   dependency chain / trans-pipe stall (was 1 wave/SIMD at ~35% issue
//   efficiency). LDS 4x (48 KB/block), VGPRs unchanged (~100) so
//   2 waves/SIMD is legal; 1 block/CU.
//
//   E_total = sum_j Gb[256,j] * ( Em(256,j)*E[255,j-1] + Wu(256,j)*E[255,j] )
// Bwd DP in reversed coords (x'_i = x[511-i], y'_j = y[511-j]):
//   Gb'[i',j'] = A'*Gb'[i'-1,j'-1] + B'*Gb'[i'-1,j'] + C'*Gb'[i',j'-1]
//   A'(i',j') = e^{2-(X~_{i'}-Y~_{j'})^2},  X~_r = x[512-r], Y~_c = y[512-c]
//   B' gate dx'_i'*(X~_i'-Y~_{j'+1}) < 0, val e^{-dx'^2}+e^{-(X~_i'-Y~_{j'+1})^2}
//   C' gate dy'_j'*(X~_{i'+1}-Y~_{j'}) > 0, val e^{-dy'^2}+e^{-(X~_{i'+1}-Y~_{j'})^2}
// (window entry m of row r = exp(2-(X~_r - Y~_{j'base+m-1})^2); B uses m+1,
//  C of row r uses row r+1's window — all verified in R14.)

#define TT 512
#define BATCH 64
#define BPB 4                    // batches per block
#define G 8
#define NPH 128                  // row-pairs per half; steps/wave = 191
#define C1F 1.2011224087864498f  // sqrt(log2 e)
#define C2F 2.8853900817779268f  // 2*log2 e
#define K2F 0.13533528323661270f // e^-2
#define LN2F 0.69314718055994531f
#define NEG_BIG (-1e30f)

#if __has_builtin(__builtin_amdgcn_exp2f)
#define EXP2F(x) __builtin_amdgcn_exp2f(x)
#else
#define EXP2F(x) __expf((x) * LN2F)
#endif

typedef float v2f __attribute__((ext_vector_type(2)));

__device__ __forceinline__ float dpp_shr1_f(float src, float old) {
  return __int_as_float(__builtin_amdgcn_update_dpp(
      __float_as_int(old), __float_as_int(src), 0x138, 0xF, 0xF, false));
}
__device__ __forceinline__ int dpp_shr1_i(int src, int old) {
  return __builtin_amdgcn_update_dpp(old, src, 0x138, 0xF, 0xF, false);
}

__global__ __launch_bounds__(512, 2) void msm_kernel(const float* __restrict__ x,
                                                     const float* __restrict__ y,
                                                     float* __restrict__ ws) {
  const int tid = threadIdx.x;
  const int w = tid >> 6;
  const int m = w >> 1;        // batch slot within block (0..3)
  const int dir = w & 1;       // 0 = fwd chain, 1 = bwd chain
  const int j = tid & 63;
  const int b = blockIdx.x * BPB + m;
  const float* xb = x + b * TT;
  const float* yb = y + b * TT;

  __shared__ float2 FXC[BPB][NPH], FDX[BPB][NPH], FEX[BPB][NPH]; // fwd rows 0..255
  __shared__ float2 BXA[BPB][NPH], BDX[BPB][NPH], BEX[BPB][NPH]; // bwd primed rows
  __shared__ float LF[BPB][TT], LG[BPB][TT], TERMS[BPB][TT];

  // ---- staging (R14 verbatim, per batch slot) ----
  if (dir == 0) {
    float4 xq = ((const float4*)xb)[j];
    float rx[4] = {xq.x, xq.y, xq.z, xq.w};
    float prev = (j > 0) ? xb[4 * j - 1] : 0.0f;
    float cc[4], dd[4], ee[4];
#pragma unroll
    for (int k = 0; k < 4; ++k) {
      float dx = rx[k] - prev;
      prev = rx[k];
      cc[k] = rx[k] * C1F;
      dd[k] = dx;
      ee[k] = __expf(-dx * dx);
    }
    FXC[m][2 * j] = make_float2(cc[0], cc[1]);
    FXC[m][2 * j + 1] = make_float2(cc[2], cc[3]);
    FDX[m][2 * j] = make_float2(dd[0], dd[1]);
    FDX[m][2 * j + 1] = make_float2(dd[2], dd[3]);
    FEX[m][2 * j] = make_float2(ee[0], ee[1]);
    FEX[m][2 * j + 1] = make_float2(ee[2], ee[3]);
  } else {
    float cc[4], dd[4], ee[4];
#pragma unroll
    for (int k = 0; k < 4; ++k) {
      int rp = 4 * j + k;
      int i1 = 512 - rp; if (i1 > 511) i1 = 511;
      int i2 = 511 - rp;
      float xa = xb[i1];
      float dxp = xb[i2] - xa;
      cc[k] = xa * C1F;
      dd[k] = dxp;
      ee[k] = __expf(-dxp * dxp);
    }
    BXA[m][2 * j] = make_float2(cc[0], cc[1]);
    BXA[m][2 * j + 1] = make_float2(cc[2], cc[3]);
    BDX[m][2 * j] = make_float2(dd[0], dd[1]);
    BDX[m][2 * j + 1] = make_float2(dd[2], dd[3]);
    BEX[m][2 * j] = make_float2(ee[0], ee[1]);
    BEX[m][2 * j + 1] = make_float2(ee[2], ee[3]);
  }
  __syncthreads();

  float EpF[G];
#pragma unroll
  for (int k = 0; k < G; ++k) EpF[k] = 0.0f;
  int kaccF = 0;

  if (dir == 0) {
    // ================= FORWARD (R14 verbatim) =================
    const float2* __restrict__ pFXC = FXC[m];
    const float2* __restrict__ pFDX = FDX[m];
    const float2* __restrict__ pFEX = FEX[m];
    float yc[G], dyS[G], edy2[G];
    {
      const float4* yv = (const float4*)yb;
      float4 a0 = yv[j * 2], a1 = yv[j * 2 + 1];
      float ry[G] = {a0.x, a0.y, a0.z, a0.w, a1.x, a1.y, a1.z, a1.w};
      float prev = (j > 0) ? yb[8 * j - 1] : 0.0f;
#pragma unroll
      for (int k = 0; k < G; ++k) {
        float dy = ry[k] - prev;
        prev = ry[k];
        yc[k] = ry[k] * C1F;
        dyS[k] = dy;
        edy2[k] = __expf(-dy * dy);
      }
    }
    float dc0 = 0.0f, dc1 = 0.0f, dc2 = 0.0f;
    float2 rdEx = pFXC[0], rdEd = pFDX[0], rdEe = pFEX[0];
    float2 rdOx, rdOd, rdOe;

    auto fstep = [&](int t, auto phc, float2& xcU, float2& dxU, float2& exU,
                     float2& xcL, float2& dxL, float2& exL) {
      constexpr int PH = decltype(phc)::value;
      {
        int pn = t + 2 - j;
        pn = (pn < 0) ? 0 : ((pn > NPH - 1) ? NPH - 1 : pn);
        xcL = pFXC[pn]; dxL = pFDX[pn]; exL = pFEX[pn];
      }
      float r0 = dpp_shr1_f(dc0, 0.0f);
      float r1 = dpp_shr1_f(dc1, 0.0f);
      float r2 = dpp_shr1_f(dc2, 0.0f);
      int k_in = dpp_shr1_i(kaccF, kaccF);
      const int p = t - j;
      if (PH == 0) {
        if (t == 0 && j == 0) r0 = K2F;
      }
      bool act = true;
      int kacc_e = kaccF;
      if (PH == 0) { act = (p >= 0); kacc_e = (p == 0) ? k_in : kaccF; }
      else if (PH == 2) { act = (p < NPH); }
      const int knew = (k_in > kacc_e) ? k_in : kacc_e;
      const float mMe = ldexpf(1.0f, kacc_e - knew);
      const float mIn = ldexpf(1.0f, k_in - knew);
      const float dv0 = r0 * mIn, dv1 = r1 * mIn, dv2 = r2 * mIn;
      const float nd0 = dc2 * mMe;
      float u[G];
#pragma unroll
      for (int k = 0; k < G; ++k) u[k] = EpF[k] * mMe;

      const v2f xcp = {xcU.x, xcU.y};
      const v2f dxp = {dxU.x, dxU.y};
      const v2f exv = {exU.x, exU.y};
      v2f Aw[G], Bw[G], Cw[G];
#define WCELL(kk)                                                       \
      {                                                                 \
        v2f s1 = xcp - yc[kk];                                          \
        v2f arg = C2F - s1 * s1;                                        \
        v2f A;                                                          \
        A.x = EXP2F(arg.x);                                             \
        A.y = EXP2F(arg.y);                                             \
        v2f Bs = A * K2F + exv;                                         \
        v2f Cs = A * K2F + edy2[kk];                                    \
        v2f gu = dxp * s1;                                              \
        v2f gl = dyS[kk] * s1;                                          \
        Aw[kk] = A;                                                     \
        Bw[kk].x = (gu.x > 0.0f) ? Bs.x : 1.0f;                         \
        Bw[kk].y = (gu.y > 0.0f) ? Bs.y : 1.0f;                         \
        Cw[kk].x = (gl.x < 0.0f) ? Cs.x : 1.0f;                         \
        Cw[kk].y = (gl.y < 0.0f) ? Cs.y : 1.0f;                         \
      }
      WCELL(0) WCELL(1) WCELL(2)
      float T0[G], T1[G];
#pragma unroll
      for (int k = 0; k < G; ++k) {
        if (k + 3 < G) WCELL(k + 3)
        __builtin_amdgcn_sched_barrier(0);
        float da = (k == 0) ? dv0 : u[k - 1];
        float pa = __fmaf_rn(da, Aw[k].x, u[k] * Bw[k].x);
        T0[k] = __fmaf_rn((k == 0) ? dv1 : T0[k - 1], Cw[k].x, pa);
        float db = (k == 0) ? dv1 : T0[k - 1];
        float pb = __fmaf_rn(db, Aw[k].y, T0[k] * Bw[k].y);
        T1[k] = __fmaf_rn((k == 0) ? dv2 : T1[k - 1], Cw[k].y, pb);
      }
#undef WCELL
      const float ndc1 = T0[G - 1];
      float m0 = fmaxf(fmaxf(T1[0], T1[1]), T1[2]);
      float m1 = fmaxf(fmaxf(T1[3], T1[4]), T1[5]);
      float m2 = fmaxf(fmaxf(T1[6], T1[7]), nd0);
      float vmax = fmaxf(fmaxf(m0, m1), fmaxf(m2, ndc1));
      unsigned ue = (__float_as_uint(vmax) >> 23) & 0xFFu;
      int e = (int)ue - 126;
      float sc = ldexpf(1.0f, -e);
      if (PH == 1) {
#pragma unroll
        for (int k = 0; k < G; ++k) EpF[k] = T1[k] * sc;
        dc0 = nd0 * sc; dc1 = ndc1 * sc; dc2 = EpF[G - 1];
        kaccF = knew + e;
      } else {
#pragma unroll
        for (int k = 0; k < G; ++k) EpF[k] = act ? T1[k] * sc : EpF[k];
        dc0 = act ? nd0 * sc : dc0;
        dc1 = act ? ndc1 * sc : dc1;
        dc2 = act ? EpF[G - 1] : dc2;
        kaccF = act ? knew + e : kaccF;
      }
    };
    std::integral_constant<int, 0> P0;
    std::integral_constant<int, 1> P1;
    std::integral_constant<int, 2> P2;
    for (int t = 0; t < 64; t += 2) {
      fstep(t, P0, rdEx, rdEd, rdEe, rdOx, rdOd, rdOe);
      fstep(t + 1, P0, rdOx, rdOd, rdOe, rdEx, rdEd, rdEe);
    }
    for (int t = 64; t < 128; t += 2) {
      fstep(t, P1, rdEx, rdEd, rdEe, rdOx, rdOd, rdOe);
      fstep(t + 1, P1, rdOx, rdOd, rdOe, rdEx, rdEd, rdEe);
    }
    for (int t = 128; t < 192; t += 2) {
      fstep(t, P2, rdEx, rdEd, rdEe, rdOx, rdOd, rdOe);
      fstep(t + 1, P2, rdOx, rdOd, rdOe, rdEx, rdEd, rdEe);
    }
#pragma unroll
    for (int k = 0; k < G; ++k) {
      float le = (EpF[k] > 0.0f) ? __logf(EpF[k]) : NEG_BIG;
      LF[m][8 * j + k] = le + (float)kaccF * LN2F - (float)(255 + 8 * j + k);
    }
  } else {
    // ============ BACKWARD (packed windows + ping-pong banks, R15) ============
    const float2* __restrict__ pBXA = BXA[m];
    const float2* __restrict__ pBDX = BDX[m];
    const float2* __restrict__ pBEX = BEX[m];
    float ycP[G + 1], dyP[G], edy2P[G];
    {
#pragma unroll
      for (int k = 0; k <= G; ++k) {
        int idx = 512 - 8 * j - k; if (idx > 511) idx = 511;
        ycP[k] = yb[idx] * C1F;
      }
#pragma unroll
      for (int k = 0; k < G; ++k) {
        int ia = 511 - 8 * j - k;
        int ib = 512 - 8 * j - k; if (ib > 511) ib = 511;
        float d = yb[ia] - yb[ib];
        dyP[k] = d;
        edy2P[k] = __expf(-d * d);
      }
    }
    float dc0 = 0.0f, dc1 = 0.0f, dc2 = 0.0f;
    // ping-pong window banks: {s,e}[G+1] each
    float sBk0[G + 1], eBk0[G + 1], sBk1[G + 1], eBk1[G + 1];
    {
      float xa0 = pBXA[0].x;
#pragma unroll
      for (int k = 0; k <= G; ++k) {
        float s = xa0 - ycP[k];
        sBk0[k] = s;
        eBk0[k] = EXP2F(C2F - s * s);
      }
    }
    float2 cxA = pBXA[0], cdx = pBDX[0], cex = pBEX[0];

    // in-bank (sU,eU) = window of row 2p; out-bank gets row 2p+2's window
    auto bstep = [&](int t, auto phc, float (&sU)[G + 1], float (&eU)[G + 1],
                     float (&sO)[G + 1], float (&eO)[G + 1]) {
      constexpr int PH = decltype(phc)::value;
      const int p = t - j;
      int pn = t + 1 - j;
      pn = (pn < 0) ? 0 : ((pn > NPH - 1) ? NPH - 1 : pn);
      float2 nxA = pBXA[pn], ndx = pBDX[pn], nex = pBEX[pn];
      float r0 = dpp_shr1_f(dc0, 0.0f);
      float r1 = dpp_shr1_f(dc1, 0.0f);
      float r2 = dpp_shr1_f(dc2, 0.0f);
      int k_in = dpp_shr1_i(kaccF, kaccF);
      const bool seed = (PH == 0) && (t == 0) && (j == 0);
      if (seed) r0 = 1.0f;                         // Gb'[0,0] = 1 (with A:=1)
      bool act = true;
      int kacc_e = kaccF;
      if (PH == 0) { act = (p >= 0); kacc_e = (p == 0) ? k_in : kaccF; }
      else if (PH == 2) { act = (p < NPH); }
      const int knew = (k_in > kacc_e) ? k_in : kacc_e;
      const float mMe = ldexpf(1.0f, kacc_e - knew);
      const float mIn = ldexpf(1.0f, k_in - knew);
      const float dv0 = r0 * mIn, dv1 = r1 * mIn, dv2 = r2 * mIn;
      const float nd0 = dc2 * mMe;
      float u[G];
#pragma unroll
      for (int k = 0; k < G; ++k) u[k] = EpF[k] * mMe;

      // packed window build: rows 2p+1 (V, local) and 2p+2 (W -> out bank)
      const v2f xbn = {cxA.y, nxA.x};
      float sV[G + 1], eV[G + 1];
#define BWIN(mm)                                                        \
      {                                                                 \
        v2f sw = xbn - ycP[mm];                                         \
        v2f arg = C2F - sw * sw;                                        \
        sV[mm] = sw.x;  eV[mm] = EXP2F(arg.x);                          \
        sO[mm] = sw.y;  eO[mm] = EXP2F(arg.y);                          \
      }
      BWIN(0) BWIN(1) BWIN(2) BWIN(3) BWIN(4)
      const float dxa = cdx.x, dxb = cdx.y, exa = cex.x, exb = cex.y;
      float T0[G], T1[G];
#pragma unroll
      for (int k = 0; k < G; ++k) {
        if (k + 5 <= G) BWIN(k + 5)
        __builtin_amdgcn_sched_barrier(0);
        float Aa = eU[k];
        if (seed && k == 0) Aa = 1.0f;
        float Ba = (dxa * sU[k + 1] < 0.0f) ? __fmaf_rn(eU[k + 1], K2F, exa) : 1.0f;
        float Ca = (dyP[k] * sV[k] > 0.0f) ? __fmaf_rn(eV[k], K2F, edy2P[k]) : 1.0f;
        float Ab = eV[k];
        float Bb = (dxb * sV[k + 1] < 0.0f) ? __fmaf_rn(eV[k + 1], K2F, exb) : 1.0f;
        float Cb = (dyP[k] * sO[k] > 0.0f) ? __fmaf_rn(eO[k], K2F, edy2P[k]) : 1.0f;
        float da = (k == 0) ? dv0 : u[k - 1];
        float pa = __fmaf_rn(da, Aa, u[k] * Ba);
        T0[k] = __fmaf_rn((k == 0) ? dv1 : T0[k - 1], Ca, pa);
        float db = (k == 0) ? dv1 : T0[k - 1];
        float pb = __fmaf_rn(db, Ab, T0[k] * Bb);
        T1[k] = __fmaf_rn((k == 0) ? dv2 : T1[k - 1], Cb, pb);
      }
#undef BWIN
      const float ndc1 = T0[G - 1];
      float m0 = fmaxf(fmaxf(T1[0], T1[1]), T1[2]);
      float m1 = fmaxf(fmaxf(T1[3], T1[4]), T1[5]);
      float m2 = fmaxf(fmaxf(T1[6], T1[7]), nd0);
      float vmax = fmaxf(fmaxf(m0, m1), fmaxf(m2, ndc1));
      unsigned ue = (__float_as_uint(vmax) >> 23) & 0xFFu;
      int e = (int)ue - 126;
      float sc = ldexpf(1.0f, -e);
      if (PH == 1) {
#pragma unroll
        for (int k = 0; k < G; ++k) EpF[k] = T1[k] * sc;
        dc0 = nd0 * sc; dc1 = ndc1 * sc; dc2 = EpF[G - 1];
        kaccF = knew + e;
      } else {
#pragma unroll
        for (int k = 0; k < G; ++k) EpF[k] = act ? T1[k] * sc : EpF[k];
        dc0 = act ? nd0 * sc : dc0;
        dc1 = act ? ndc1 * sc : dc1;
        dc2 = act ? EpF[G - 1] : dc2;
        kaccF = act ? knew + e : kaccF;
      }
      cxA = nxA; cdx = ndx; cex = nex;    // small rotation (3 float2)
    };
    std::integral_constant<int, 0> P0;
    std::integral_constant<int, 1> P1;
    std::integral_constant<int, 2> P2;
    for (int t = 0; t < 64; t += 2) {
      bstep(t, P0, sBk0, eBk0, sBk1, eBk1);
      bstep(t + 1, P0, sBk1, eBk1, sBk0, eBk0);
    }
    for (int t = 64; t < 128; t += 2) {
      bstep(t, P1, sBk0, eBk0, sBk1, eBk1);
      bstep(t + 1, P1, sBk1, eBk1, sBk0, eBk0);
    }
    for (int t = 128; t < 192; t += 2) {       // t=191 inert (all p >= NPH)
      bstep(t, P2, sBk0, eBk0, sBk1, eBk1);
      bstep(t + 1, P2, sBk1, eBk1, sBk0, eBk0);
    }
#pragma unroll
    for (int k = 0; k < G; ++k) {
      float le = (EpF[k] > 0.0f) ? __logf(EpF[k]) : NEG_BIG;
      LG[m][511 - (8 * j + k)] = le + (float)kaccF * LN2F - (float)(255 + 8 * j + k);
    }
  }
  __syncthreads();

  // ---- combine (R14 verbatim, per batch slot: 128 threads each) ----
  {
    const int gt = tid & 127;
    const float sx = xb[256];
    const float dxs = sx - xb[255];
    const float ex2s = __expf(-dxs * dxs);
#pragma unroll
    for (int c = 0; c < 4; ++c) {
      int jj = 4 * gt + c;
      float d = sx - yb[jj];
      float m2 = d * d;
      float lw = (dxs * d > 0.0f) ? __logf(ex2s + __expf(-m2)) : 0.0f;
      float t1 = ((jj > 0) ? LF[m][jj - 1] : NEG_BIG) - m2;
      float t2 = LF[m][jj] - 1.0f + lw;
      float mt = fmaxf(t1, t2);
      float term = NEG_BIG;
      if (mt > -1e29f)
        term = LG[m][jj] + mt + __logf(__expf(t1 - mt) + __expf(t2 - mt));
      TERMS[m][jj] = term;
    }
  }
  __syncthreads();
  if (dir == 0) {
    float v[8];
    float M = NEG_BIG;
#pragma unroll
    for (int i = 0; i < 8; ++i) {
      v[i] = TERMS[m][8 * j + i];
      M = fmaxf(M, v[i]);
    }
#pragma unroll
    for (int off = 1; off < 64; off <<= 1) M = fmaxf(M, __shfl_xor(M, off));
    float S = 0.0f;
#pragma unroll
    for (int i = 0; i < 8; ++i) S += __expf(v[i] - M);
#pragma unroll
    for (int off = 1; off < 64; off <<= 1) S += __shfl_xor(S, off);
    if (j == 0) ws[b] = -(M + __logf(S));
  }
}

__global__ __launch_bounds__(64) void reduce_kernel(const float* __restrict__ ws,
                                                    float* __restrict__ out) {
  float v = ws[threadIdx.x];
#pragma unroll
  for (int off = 32; off > 0; off >>= 1) v += __shfl_down(v, off);
  if (threadIdx.x == 0) out[0] = v * (1.0f / BATCH);
}

extern "C" void kernel_launch(void* const* d_in, const int* in_sizes, int n_in,
                              void* d_out, int out_size, void* d_ws, size_t ws_size,
                              hipStream_t stream) {
  const float* x = (const float*)d_in[0];
  const float* y = (const float*)d_in[1];
  float* ws = (float*)d_ws;
  float* out = (float*)d_out;
  msm_kernel<<<BATCH / BPB, 512, 0, stream>>>(x, y, ws);
  reduce_kernel<<<1, 64, 0, stream>>>(ws, out);
}

// Round 2
// 161.609 us; speedup vs baseline: 1.4575x; 1.4575x over previous
//
#include <hip/hip_runtime.h>
#include <math.h>
#include <type_traits>

// SoftMSM loss on MI355X — round 17.
// R15 config restored (64 blocks x 128 thr, 1 chain/SIMD; R16's 2-chain/SIMD
// co-residence regressed: per-SIMD issue was already 61% -> 90% saturated).
// New: cross-step software pipeline of window construction.
//   - fwd: WCELL(0..2) of step t+1 built at step t's tail from the L-bank
//     just loaded (identical inputs; Aw/Bw/Cw persistent across steps).
//   - bwd: BWIN(0..4) of step t+1 built at step t's tail; LDS prefetch
//     deepened one step (xA2 = BXA[t+2-j], rotation cxA<-nxA<-xA2) so
//     {nxA.y, xA2.x} == old step-(t+1) {cxA.y, nxA.x}. sV/eV persistent.
//   The tail windows sit in the same scheduling region as the serial renorm
//   (vmax tree -> exponent extract -> rescale) and step-boundary chain,
//   giving the lone wave ~130 cyc of independent issue to fill those stalls.
//
//   E_total = sum_j Gb[256,j] * ( Em(256,j)*E[255,j-1] + Wu(256,j)*E[255,j] )
// Bwd DP in reversed coords (x'_i = x[511-i], y'_j = y[511-j]):
//   Gb'[i',j'] = A'*Gb'[i'-1,j'-1] + B'*Gb'[i'-1,j'] + C'*Gb'[i',j'-1]
//   (window entry m of row r = exp(2-(X~_r - Y~_{j'base+m-1})^2); B uses m+1,
//    C of row r uses row r+1's window — all verified in R14.)

#define TT 512
#define BATCH 64
#define G 8
#define NPH 128                  // row-pairs per half; steps/wave = 191
#define C1F 1.2011224087864498f  // sqrt(log2 e)
#define C2F 2.8853900817779268f  // 2*log2 e
#define K2F 0.13533528323661270f // e^-2
#define LN2F 0.69314718055994531f
#define NEG_BIG (-1e30f)

#if __has_builtin(__builtin_amdgcn_exp2f)
#define EXP2F(x) __builtin_amdgcn_exp2f(x)
#else
#define EXP2F(x) __expf((x) * LN2F)
#endif

typedef float v2f __attribute__((ext_vector_type(2)));

__device__ __forceinline__ float dpp_shr1_f(float src, float old) {
  return __int_as_float(__builtin_amdgcn_update_dpp(
      __float_as_int(old), __float_as_int(src), 0x138, 0xF, 0xF, false));
}
__device__ __forceinline__ int dpp_shr1_i(int src, int old) {
  return __builtin_amdgcn_update_dpp(old, src, 0x138, 0xF, 0xF, false);
}

__global__ __launch_bounds__(128, 1) void msm_kernel(const float* __restrict__ x,
                                                     const float* __restrict__ y,
                                                     float* __restrict__ ws) {
  const int b = blockIdx.x;
  const int tid = threadIdx.x;
  const int wv = tid >> 6;
  const int j = tid & 63;
  const float* xb = x + b * TT;
  const float* yb = y + b * TT;

  __shared__ float2 FXC[NPH], FDX[NPH], FEX[NPH];   // fwd rows 0..255
  __shared__ float2 BXA[NPH], BDX[NPH], BEX[NPH];   // bwd primed rows 0..255
  __shared__ float LF[TT], LG[TT], TERMS[TT];

  // ---- staging (R14 verbatim) ----
  if (wv == 0) {
    float4 xq = ((const float4*)xb)[j];
    float rx[4] = {xq.x, xq.y, xq.z, xq.w};
    float prev = (j > 0) ? xb[4 * j - 1] : 0.0f;
    float cc[4], dd[4], ee[4];
#pragma unroll
    for (int k = 0; k < 4; ++k) {
      float dx = rx[k] - prev;
      prev = rx[k];
      cc[k] = rx[k] * C1F;
      dd[k] = dx;
      ee[k] = __expf(-dx * dx);
    }
    FXC[2 * j] = make_float2(cc[0], cc[1]);
    FXC[2 * j + 1] = make_float2(cc[2], cc[3]);
    FDX[2 * j] = make_float2(dd[0], dd[1]);
    FDX[2 * j + 1] = make_float2(dd[2], dd[3]);
    FEX[2 * j] = make_float2(ee[0], ee[1]);
    FEX[2 * j + 1] = make_float2(ee[2], ee[3]);
  } else {
    float cc[4], dd[4], ee[4];
#pragma unroll
    for (int k = 0; k < 4; ++k) {
      int rp = 4 * j + k;
      int i1 = 512 - rp; if (i1 > 511) i1 = 511;
      int i2 = 511 - rp;
      float xa = xb[i1];
      float dxp = xb[i2] - xa;
      cc[k] = xa * C1F;
      dd[k] = dxp;
      ee[k] = __expf(-dxp * dxp);
    }
    BXA[2 * j] = make_float2(cc[0], cc[1]);
    BXA[2 * j + 1] = make_float2(cc[2], cc[3]);
    BDX[2 * j] = make_float2(dd[0], dd[1]);
    BDX[2 * j + 1] = make_float2(dd[2], dd[3]);
    BEX[2 * j] = make_float2(ee[0], ee[1]);
    BEX[2 * j + 1] = make_float2(ee[2], ee[3]);
  }
  __syncthreads();

  float EpF[G];
#pragma unroll
  for (int k = 0; k < G; ++k) EpF[k] = 0.0f;
  int kaccF = 0;

  if (wv == 0) {
    // ================= FORWARD (pipelined windows) =================
    float yc[G], dyS[G], edy2[G];
    {
      const float4* yv = (const float4*)yb;
      float4 a0 = yv[j * 2], a1 = yv[j * 2 + 1];
      float ry[G] = {a0.x, a0.y, a0.z, a0.w, a1.x, a1.y, a1.z, a1.w};
      float prev = (j > 0) ? yb[8 * j - 1] : 0.0f;
#pragma unroll
      for (int k = 0; k < G; ++k) {
        float dy = ry[k] - prev;
        prev = ry[k];
        yc[k] = ry[k] * C1F;
        dyS[k] = dy;
        edy2[k] = __expf(-dy * dy);
      }
    }
    float dc0 = 0.0f, dc1 = 0.0f, dc2 = 0.0f;
    float2 rdEx = FXC[0], rdEd = FDX[0], rdEe = FEX[0];
    float2 rdOx, rdOd, rdOe;

    // persistent window banks (live across steps)
    v2f Aw[G], Bw[G], Cw[G];

#define WCELL(kk)                                                       \
    {                                                                   \
      v2f s1 = xcp - yc[kk];                                            \
      v2f arg = C2F - s1 * s1;                                          \
      v2f A;                                                            \
      A.x = EXP2F(arg.x);                                               \
      A.y = EXP2F(arg.y);                                               \
      v2f Bs = A * K2F + exv;                                           \
      v2f Cs = A * K2F + edy2[kk];                                      \
      v2f gu = dxp * s1;                                                \
      v2f gl = dyS[kk] * s1;                                            \
      Aw[kk] = A;                                                       \
      Bw[kk].x = (gu.x > 0.0f) ? Bs.x : 1.0f;                           \
      Bw[kk].y = (gu.y > 0.0f) ? Bs.y : 1.0f;                           \
      Cw[kk].x = (gl.x < 0.0f) ? Cs.x : 1.0f;                           \
      Cw[kk].y = (gl.y < 0.0f) ? Cs.y : 1.0f;                           \
    }

    // prologue: windows 0..2 for step 0 (from the preloaded E bank)
    {
      v2f xcp = {rdEx.x, rdEx.y};
      v2f dxp = {rdEd.x, rdEd.y};
      v2f exv = {rdEe.x, rdEe.y};
      WCELL(0) WCELL(1) WCELL(2)
    }

    auto fstep = [&](int t, auto phc, float2& xcU, float2& dxU, float2& exU,
                     float2& xcL, float2& dxL, float2& exL) {
      constexpr int PH = decltype(phc)::value;
      {
        int pn = t + 2 - j;
        pn = (pn < 0) ? 0 : ((pn > NPH - 1) ? NPH - 1 : pn);
        xcL = FXC[pn]; dxL = FDX[pn]; exL = FEX[pn];
      }
      float r0 = dpp_shr1_f(dc0, 0.0f);
      float r1 = dpp_shr1_f(dc1, 0.0f);
      float r2 = dpp_shr1_f(dc2, 0.0f);
      int k_in = dpp_shr1_i(kaccF, kaccF);
      const int p = t - j;
      if (PH == 0) {
        if (t == 0 && j == 0) r0 = K2F;
      }
      bool act = true;
      int kacc_e = kaccF;
      if (PH == 0) { act = (p >= 0); kacc_e = (p == 0) ? k_in : kaccF; }
      else if (PH == 2) { act = (p < NPH); }
      const int knew = (k_in > kacc_e) ? k_in : kacc_e;
      const float mMe = ldexpf(1.0f, kacc_e - knew);
      const float mIn = ldexpf(1.0f, k_in - knew);
      const float dv0 = r0 * mIn, dv1 = r1 * mIn, dv2 = r2 * mIn;
      const float nd0 = dc2 * mMe;
      float u[G];
#pragma unroll
      for (int k = 0; k < G; ++k) u[k] = EpF[k] * mMe;

      v2f xcp = {xcU.x, xcU.y};
      v2f dxp = {dxU.x, dxU.y};
      v2f exv = {exU.x, exU.y};
      // windows 0..2 were built at the previous step's tail
      float T0[G], T1[G];
#pragma unroll
      for (int k = 0; k < G; ++k) {
        if (k + 3 < G) WCELL(k + 3)
        __builtin_amdgcn_sched_barrier(0);
        float da = (k == 0) ? dv0 : u[k - 1];
        float pa = __fmaf_rn(da, Aw[k].x, u[k] * Bw[k].x);
        T0[k] = __fmaf_rn((k == 0) ? dv1 : T0[k - 1], Cw[k].x, pa);
        float db = (k == 0) ? dv1 : T0[k - 1];
        float pb = __fmaf_rn(db, Aw[k].y, T0[k] * Bw[k].y);
        T1[k] = __fmaf_rn((k == 0) ? dv2 : T1[k - 1], Cw[k].y, pb);
      }
      const float ndc1 = T0[G - 1];
      float m0 = fmaxf(fmaxf(T1[0], T1[1]), T1[2]);
      float m1 = fmaxf(fmaxf(T1[3], T1[4]), T1[5]);
      float m2 = fmaxf(fmaxf(T1[6], T1[7]), nd0);
      float vmax = fmaxf(fmaxf(m0, m1), fmaxf(m2, ndc1));
      unsigned ue = (__float_as_uint(vmax) >> 23) & 0xFFu;
      int e = (int)ue - 126;
      float sc = ldexpf(1.0f, -e);
      if (PH == 1) {
#pragma unroll
        for (int k = 0; k < G; ++k) EpF[k] = T1[k] * sc;
        dc0 = nd0 * sc; dc1 = ndc1 * sc; dc2 = EpF[G - 1];
        kaccF = knew + e;
      } else {
#pragma unroll
        for (int k = 0; k < G; ++k) EpF[k] = act ? T1[k] * sc : EpF[k];
        dc0 = act ? nd0 * sc : dc0;
        dc1 = act ? ndc1 * sc : dc1;
        dc2 = act ? EpF[G - 1] : dc2;
        kaccF = act ? knew + e : kaccF;
      }
      // tail: build next step's windows 0..2 from the L bank just loaded.
      // Sits in the same scheduling region as the serial renorm above.
      xcp.x = xcL.x; xcp.y = xcL.y;
      dxp.x = dxL.x; dxp.y = dxL.y;
      exv.x = exL.x; exv.y = exL.y;
      WCELL(0) WCELL(1) WCELL(2)
    };
#undef WCELL
    std::integral_constant<int, 0> P0;
    std::integral_constant<int, 1> P1;
    std::integral_constant<int, 2> P2;
    for (int t = 0; t < 64; t += 2) {
      fstep(t, P0, rdEx, rdEd, rdEe, rdOx, rdOd, rdOe);
      fstep(t + 1, P0, rdOx, rdOd, rdOe, rdEx, rdEd, rdEe);
    }
    for (int t = 64; t < 128; t += 2) {
      fstep(t, P1, rdEx, rdEd, rdEe, rdOx, rdOd, rdOe);
      fstep(t + 1, P1, rdOx, rdOd, rdOe, rdEx, rdEd, rdEe);
    }
    for (int t = 128; t < 192; t += 2) {
      fstep(t, P2, rdEx, rdEd, rdEe, rdOx, rdOd, rdOe);
      fstep(t + 1, P2, rdOx, rdOd, rdOe, rdEx, rdEd, rdEe);
    }
#pragma unroll
    for (int k = 0; k < G; ++k) {
      float le = (EpF[k] > 0.0f) ? __logf(EpF[k]) : NEG_BIG;
      LF[8 * j + k] = le + (float)kaccF * LN2F - (float)(255 + 8 * j + k);
    }
  } else {
    // ============ BACKWARD (pipelined windows, deepened prefetch) ============
    float ycP[G + 1], dyP[G], edy2P[G];
    {
#pragma unroll
      for (int k = 0; k <= G; ++k) {
        int idx = 512 - 8 * j - k; if (idx > 511) idx = 511;
        ycP[k] = yb[idx] * C1F;
      }
#pragma unroll
      for (int k = 0; k < G; ++k) {
        int ia = 511 - 8 * j - k;
        int ib = 512 - 8 * j - k; if (ib > 511) ib = 511;
        float d = yb[ia] - yb[ib];
        dyP[k] = d;
        edy2P[k] = __expf(-d * d);
      }
    }
    float dc0 = 0.0f, dc1 = 0.0f, dc2 = 0.0f;
    // ping-pong window banks: {s,e}[G+1] each; V persistent across steps
    float sBk0[G + 1], eBk0[G + 1], sBk1[G + 1], eBk1[G + 1];
    float sV[G + 1], eV[G + 1];
    {
      float xa0 = BXA[0].x;
#pragma unroll
      for (int k = 0; k <= G; ++k) {
        float s = xa0 - ycP[k];
        sBk0[k] = s;
        eBk0[k] = EXP2F(C2F - s * s);
      }
    }
    float2 cxA = BXA[0], cdx = BDX[0], cex = BEX[0];
    float2 nxA, ndx, nex;
    {
      int pn = 1 - j;
      pn = (pn < 0) ? 0 : pn;
      nxA = BXA[pn]; ndx = BDX[pn]; nex = BEX[pn];
    }
    // prologue: V_0[0..4] and U_1[0..4] (bank1), old step-0 BWIN(0..4)
    {
      float xb0 = cxA.y, xb1 = nxA.x;
#pragma unroll
      for (int mm = 0; mm < 5; ++mm) {
        float s0 = xb0 - ycP[mm]; sV[mm] = s0; eV[mm] = EXP2F(C2F - s0 * s0);
        float s1 = xb1 - ycP[mm]; sBk1[mm] = s1; eBk1[mm] = EXP2F(C2F - s1 * s1);
      }
    }

    // in-bank (sU,eU) = window of row 2p; k-loop fills out-bank[5..8];
    // tail fills sV/eV[0..4] (next step) and sU/eU[0..4] (step t+2's U).
    auto bstep = [&](int t, auto phc, float (&sU)[G + 1], float (&eU)[G + 1],
                     float (&sO)[G + 1], float (&eO)[G + 1]) {
      constexpr int PH = decltype(phc)::value;
      const int p = t - j;
      int pn2 = t + 2 - j;
      pn2 = (pn2 < 0) ? 0 : ((pn2 > NPH - 1) ? NPH - 1 : pn2);
      float2 xA2 = BXA[pn2], dx2 = BDX[pn2], ex2 = BEX[pn2];
      float r0 = dpp_shr1_f(dc0, 0.0f);
      float r1 = dpp_shr1_f(dc1, 0.0f);
      float r2 = dpp_shr1_f(dc2, 0.0f);
      int k_in = dpp_shr1_i(kaccF, kaccF);
      const bool seed = (PH == 0) && (t == 0) && (j == 0);
      if (seed) r0 = 1.0f;                         // Gb'[0,0] = 1 (with A:=1)
      bool act = true;
      int kacc_e = kaccF;
      if (PH == 0) { act = (p >= 0); kacc_e = (p == 0) ? k_in : kaccF; }
      else if (PH == 2) { act = (p < NPH); }
      const int knew = (k_in > kacc_e) ? k_in : kacc_e;
      const float mMe = ldexpf(1.0f, kacc_e - knew);
      const float mIn = ldexpf(1.0f, k_in - knew);
      const float dv0 = r0 * mIn, dv1 = r1 * mIn, dv2 = r2 * mIn;
      const float nd0 = dc2 * mMe;
      float u[G];
#pragma unroll
      for (int k = 0; k < G; ++k) u[k] = EpF[k] * mMe;

      // window entries 0..4 (V and O) were built at the previous step's tail
      const v2f xbn = {cxA.y, nxA.x};
#define BWIN(mm)                                                        \
      {                                                                 \
        v2f sw = xbn - ycP[mm];                                         \
        v2f arg = C2F - sw * sw;                                        \
        sV[mm] = sw.x;  eV[mm] = EXP2F(arg.x);                          \
        sO[mm] = sw.y;  eO[mm] = EXP2F(arg.y);                          \
      }
      const float dxa = cdx.x, dxb = cdx.y, exa = cex.x, exb = cex.y;
      float T0[G], T1[G];
#pragma unroll
      for (int k = 0; k < G; ++k) {
        if (k + 5 <= G) BWIN(k + 5)
        __builtin_amdgcn_sched_barrier(0);
        float Aa = eU[k];
        if (seed && k == 0) Aa = 1.0f;
        float Ba = (dxa * sU[k + 1] < 0.0f) ? __fmaf_rn(eU[k + 1], K2F, exa) : 1.0f;
        float Ca = (dyP[k] * sV[k] > 0.0f) ? __fmaf_rn(eV[k], K2F, edy2P[k]) : 1.0f;
        float Ab = eV[k];
        float Bb = (dxb * sV[k + 1] < 0.0f) ? __fmaf_rn(eV[k + 1], K2F, exb) : 1.0f;
        float Cb = (dyP[k] * sO[k] > 0.0f) ? __fmaf_rn(eO[k], K2F, edy2P[k]) : 1.0f;
        float da = (k == 0) ? dv0 : u[k - 1];
        float pa = __fmaf_rn(da, Aa, u[k] * Ba);
        T0[k] = __fmaf_rn((k == 0) ? dv1 : T0[k - 1], Ca, pa);
        float db = (k == 0) ? dv1 : T0[k - 1];
        float pb = __fmaf_rn(db, Ab, T0[k] * Bb);
        T1[k] = __fmaf_rn((k == 0) ? dv2 : T1[k - 1], Cb, pb);
      }
#undef BWIN
      const float ndc1 = T0[G - 1];
      float m0 = fmaxf(fmaxf(T1[0], T1[1]), T1[2]);
      float m1 = fmaxf(fmaxf(T1[3], T1[4]), T1[5]);
      float m2 = fmaxf(fmaxf(T1[6], T1[7]), nd0);
      float vmax = fmaxf(fmaxf(m0, m1), fmaxf(m2, ndc1));
      unsigned ue = (__float_as_uint(vmax) >> 23) & 0xFFu;
      int e = (int)ue - 126;
      float sc = ldexpf(1.0f, -e);
      if (PH == 1) {
#pragma unroll
        for (int k = 0; k < G; ++k) EpF[k] = T1[k] * sc;
        dc0 = nd0 * sc; dc1 = ndc1 * sc; dc2 = EpF[G - 1];
        kaccF = knew + e;
      } else {
#pragma unroll
        for (int k = 0; k < G; ++k) EpF[k] = act ? T1[k] * sc : EpF[k];
        dc0 = act ? nd0 * sc : dc0;
        dc1 = act ? ndc1 * sc : dc1;
        dc2 = act ? EpF[G - 1] : dc2;
        kaccF = act ? knew + e : kaccF;
      }
      // tail: next step's BWIN(0..4) — V_{t+1}[0..4] and (via sU/eU, the
      // out-bank of step t+1) U_{t+2}[0..4]. {nxA.y, xA2.x} equals the old
      // step-(t+1) {cxA.y, nxA.x}. Overlaps the serial renorm above.
      {
        float xb0 = nxA.y, xb1 = xA2.x;
#pragma unroll
        for (int mm = 0; mm < 5; ++mm) {
          float s0 = xb0 - ycP[mm]; sV[mm] = s0; eV[mm] = EXP2F(C2F - s0 * s0);
          float s1 = xb1 - ycP[mm]; sU[mm] = s1; eU[mm] = EXP2F(C2F - s1 * s1);
        }
      }
      cxA = nxA; cdx = ndx; cex = nex;    // rotate (depth-2 prefetch)
      nxA = xA2; ndx = dx2; nex = ex2;
    };
    std::integral_constant<int, 0> P0;
    std::integral_constant<int, 1> P1;
    std::integral_constant<int, 2> P2;
    for (int t = 0; t < 64; t += 2) {
      bstep(t, P0, sBk0, eBk0, sBk1, eBk1);
      bstep(t + 1, P0, sBk1, eBk1, sBk0, eBk0);
    }
    for (int t = 64; t < 128; t += 2) {
      bstep(t, P1, sBk0, eBk0, sBk1, eBk1);
      bstep(t + 1, P1, sBk1, eBk1, sBk0, eBk0);
    }
    for (int t = 128; t < 192; t += 2) {       // t=191 inert (all p >= NPH)
      bstep(t, P2, sBk0, eBk0, sBk1, eBk1);
      bstep(t + 1, P2, sBk1, eBk1, sBk0, eBk0);
    }
#pragma unroll
    for (int k = 0; k < G; ++k) {
      float le = (EpF[k] > 0.0f) ? __logf(EpF[k]) : NEG_BIG;
      LG[511 - (8 * j + k)] = le + (float)kaccF * LN2F - (float)(255 + 8 * j + k);
    }
  }
  __syncthreads();

  // ---- combine (R14 verbatim) ----
  {
    const float sx = xb[256];
    const float dxs = sx - xb[255];
    const float ex2s = __expf(-dxs * dxs);
#pragma unroll
    for (int c = 0; c < 4; ++c) {
      int jj = 4 * tid + c;
      float d = sx - yb[jj];
      float m2 = d * d;
      float lw = (dxs * d > 0.0f) ? __logf(ex2s + __expf(-m2)) : 0.0f;
      float t1 = ((jj > 0) ? LF[jj - 1] : NEG_BIG) - m2;
      float t2 = LF[jj] - 1.0f + lw;
      float mt = fmaxf(t1, t2);
      float term = NEG_BIG;
      if (mt > -1e29f)
        term = LG[jj] + mt + __logf(__expf(t1 - mt) + __expf(t2 - mt));
      TERMS[jj] = term;
    }
  }
  __syncthreads();
  if (wv == 0) {
    float v[8];
    float M = NEG_BIG;
#pragma unroll
    for (int i = 0; i < 8; ++i) {
      v[i] = TERMS[8 * j + i];
      M = fmaxf(M, v[i]);
    }
#pragma unroll
    for (int off = 1; off < 64; off <<= 1) M = fmaxf(M, __shfl_xor(M, off));
    float S = 0.0f;
#pragma unroll
    for (int i = 0; i < 8; ++i) S += __expf(v[i] - M);
#pragma unroll
    for (int off = 1; off < 64; off <<= 1) S += __shfl_xor(S, off);
    if (j == 0) ws[b] = -(M + __logf(S));
  }
}

__global__ __launch_bounds__(64) void reduce_kernel(const float* __restrict__ ws,
                                                    float* __restrict__ out) {
  float v = ws[threadIdx.x];
#pragma unroll
  for (int off = 32; off > 0; off >>= 1) v += __shfl_down(v, off);
  if (threadIdx.x == 0) out[0] = v * (1.0f / BATCH);
}

extern "C" void kernel_launch(void* const* d_in, const int* in_sizes, int n_in,
                              void* d_out, int out_size, void* d_ws, size_t ws_size,
                              hipStream_t stream) {
  const float* x = (const float*)d_in[0];
  const float* y = (const float*)d_in[1];
  float* ws = (float*)d_ws;
  float* out = (float*)d_out;
  msm_kernel<<<BATCH, 128, 0, stream>>>(x, y, ws);
  reduce_kernel<<<1, 64, 0, stream>>>(ws, out);
}